// Round 11
// baseline (248.926 us; speedup 1.0000x reference)
//
#include <hip/hip_runtime.h>
#include <math.h>

#define BB 8
#define LL 64
#define NP 63          // frame pairs per batch
#define MM 16          // sampled frames
#define HH 112
#define WW 112
#define HW (HH*WW)
#define CIN 3
#define CMID 8
#define COUT 3
#define NTH 448        // 112 rows x 4 col-groups of 4 px
#define TROWS 118      // 112 + 6 row halo
#define TCOLS 24       // 4 pad | 112 interior | 4 (incl right pad/halo)
#define NCHUNK 2124    // 3 * 118 * 6 float4-chunks
#define CPC 708        // chunks per channel (118*6)
#define NSTR 7         // column strips per frame

// workspace byte offsets
#define WS_SCORES 0        // double[504*7] = 28224
#define WS_IDX    28672    // int[128]
#define WS_WT     29184    // float[1176]  score weights [cky][kx][o=8]
#define WS_WC     34048    // float[588]   combined weights [cky][kx][o pad4]
#define WS_BIAS2  36480    // float[4]
#define WS_PART   36608    // float[896*6] = 21504 (ends 58112)
#define WS_STATS  58112    // float[6]
#define WS_CNT    58240    // int[1] last-block ticket
#define WS_ZERO   58368    // float[256] zero page

#define PD_EPS 1e-6f
#define BN_EPS 1e-5f

// ---------------------------------------------------------------- prep
__global__ void prep_kernel(const float* __restrict__ cw, const float* __restrict__ cb,
                            const float* __restrict__ bw, char* __restrict__ ws)
{
    float* wT = (float*)(ws + WS_WT);
    float* wc = (float*)(ws + WS_WC);
    float* b2 = (float*)(ws + WS_BIAS2);
    float* zp = (float*)(ws + WS_ZERO);
    int tid = threadIdx.x;
    zp[tid] = 0.f;
    if (tid == 0) *(int*)(ws + WS_CNT) = 0;   // re-zero ticket every launch
    for (int i = tid; i < CIN*49*CMID; i += 256) {
        int cky = i / 56, r = i % 56, kx = r / 8, o = r % 8;
        int c = cky / 7, ky = cky % 7;
        wT[i] = cw[((o*CIN + c)*7 + ky)*7 + kx];
    }
    for (int i = tid; i < CIN*49; i += 256) {
        int c = i / 49, ky = (i / 7) % 7, kx = i % 7;
        for (int o = 0; o < COUT; ++o) {
            float s = 0.f;
            for (int m = 0; m < CMID; ++m)
                s += bw[o*CMID + m] * cw[((m*CIN + c)*7 + ky)*7 + kx];
            wc[(c*7 + ky)*28 + kx*4 + o] = s;
        }
        wc[(c*7 + ky)*28 + kx*4 + 3] = 0.f;
    }
    if (tid < COUT) {
        float s = 0.f;
        for (int m = 0; m < CMID; ++m) s += bw[tid*CMID + m] * cb[m];
        b2[tid] = s;
    }
}

// chunk idx -> tile/global coords. tile row t <-> global row t-3.
#define CHUNK_ADDR                                                           \
    int idx = tid + k*NTH;                                                   \
    int c   = idx / CPC;                                                     \
    int rem = idx - c*CPC;                                                   \
    int row = rem / 6;                                                       \
    int q   = rem - row*6;                                                   \
    int gr  = row - 3;                                                       \
    int gc  = x0col + q*4;                                                   \
    bool vld = (idx < NCHUNK) & ((unsigned)gr < HH) & ((unsigned)gc <= 108); \
    int off = c*HW + gr*WW + gc;                                             \
    int li  = c*(TROWS*TCOLS) + row*TCOLS + q*4;

// ---------------------------------------------------------------- scores
// block = one pair x one 16-col full-height strip. Single LDS stage of the
// diff image, ONE barrier, barrier-free FMA phase; 4 blocks/CU = 28 waves.
// Weights via contiguous uniform s_load -> SGPR FMA operands.
__global__ __launch_bounds__(NTH) void score_kernel(
    const float* __restrict__ x, char* __restrict__ ws)
{
    __shared__ __align__(16) float tile[CIN][TROWS][TCOLS];   // 33984 B
    __shared__ double sred[7];
    const float* wT = (const float*)(ws + WS_WT);
    const float* zp = (const float*)(ws + WS_ZERO);
    double* scores  = (double*)(ws + WS_SCORES);

    int B = blockIdx.x;                        // 3528 blocks, 3528%8==0
    int work = (B & 7) * 441 + (B >> 3);       // XCD-chunked swizzle
    int pair = work / NSTR, strip = work - pair*NSTR;
    int b = pair / NP, t = pair - b*NP;
    const float* x0 = x + (size_t)(b*LL + t) * (CIN*HW);
    const float* x1 = x0 + CIN*HW;
    int x0col = strip*16 - 4;

    int tid = threadIdx.x;
    int r  = tid >> 2;          // output row 0..111
    int cg = tid & 3;           // col group

    float* tf = &tile[0][0][0];
    #pragma unroll
    for (int k = 0; k < 5; ++k) {
        CHUNK_ADDR;
        const float* pa = vld ? (x0 + off) : zp;
        const float* pb = vld ? (x1 + off) : zp;
        float4 va = *(const float4*)pa;
        float4 vb = *(const float4*)pb;
        float4 d;
        d.x = va.x - vb.x; d.y = va.y - vb.y;
        d.z = va.z - vb.z; d.w = va.w - vb.w;
        if (idx < NCHUNK) *(float4*)&tf[li] = d;
    }
    __syncthreads();

    float acc[4][8];
    #pragma unroll
    for (int p = 0; p < 4; ++p)
        #pragma unroll
        for (int o = 0; o < 8; ++o) acc[p][o] = 0.f;

    #pragma unroll 1
    for (int cky = 0; cky < 21; ++cky) {
        int c = cky / 7, ky = cky % 7;
        const float* tr = &tile[c][r + ky][cg*4];
        float v[12];
        *(float4*)&v[0] = *(const float4*)&tr[0];
        *(float4*)&v[4] = *(const float4*)&tr[4];
        *(float4*)&v[8] = *(const float4*)&tr[8];
        const float* wrow = wT + cky*56;              // uniform -> s_load
        #pragma unroll
        for (int kx = 0; kx < 7; ++kx) {
            #pragma unroll
            for (int o = 0; o < 8; ++o) {
                float wv = wrow[kx*8 + o];            // SGPR operand
                #pragma unroll
                for (int p = 0; p < 4; ++p)
                    acc[p][o] += wv * v[p + kx + 1];
            }
        }
    }

    double dacc = 0.0;
    #pragma unroll
    for (int p = 0; p < 4; ++p) {
        float ss = 0.f;
        #pragma unroll
        for (int o = 0; o < 8; ++o) {
            float d = acc[p][o] + PD_EPS;
            ss += d*d;
        }
        dacc += (double)sqrtf(ss);
    }

    #pragma unroll
    for (int off2 = 32; off2 > 0; off2 >>= 1)
        dacc += __shfl_down(dacc, off2, 64);
    int wid = tid >> 6, lane = tid & 63;
    if (lane == 0) sred[wid] = dacc;
    __syncthreads();
    if (tid == 0) {
        double ssum = 0.0;
        for (int w = 0; w < 7; ++w) ssum += sred[w];
        scores[pair*NSTR + strip] = ssum;
    }
}

// ---------------------------------------------------------------- sampling
__global__ void sample_kernel(char* __restrict__ ws)
{
    __shared__ double cum[BB][NP];
    const double* scores = (const double*)(ws + WS_SCORES);
    int* idxs = (int*)(ws + WS_IDX);
    int tid = threadIdx.x;                // 128
    if (tid < BB) {
        double tot = 0.0;
        for (int t = 0; t < NP; ++t) {
            const double* sp = scores + (tid*NP + t)*NSTR;
            double s = 0.0;
            for (int u = 0; u < NSTR; ++u) s += sp[u];
            tot += sqrt(s);
        }
        double run = 0.0;
        for (int t = 0; t < NP; ++t) {
            const double* sp = scores + (tid*NP + t)*NSTR;
            double s = 0.0;
            for (int u = 0; u < NSTR; ++u) s += sp[u];
            run += sqrt(s) / tot;
            cum[tid][t] = run;
        }
    }
    __syncthreads();
    {
        int b = tid / MM, m = tid % MM;
        double target = (double)((float)m / 15.f);
        int best = 0;
        double bv = fabs(cum[b][0] - target);
        for (int t = 1; t < NP; ++t) {
            double v = fabs(cum[b][t] - target);
            if (v < bv) { bv = v; best = t; }   // strict: first min wins
        }
        idxs[tid] = best;
    }
}

// ---------------------------------------------------------------- resblock conv
// block = one selected frame x one strip; single-stage structure.
// combined 7x7 3->3; y -> d_out + BN partials. The LAST block to finish
// (atomic ticket) reduces part[896][6] -> stats (saves the statreduce launch).
__global__ __launch_bounds__(NTH) void resconv_kernel(
    const float* __restrict__ x, char* __restrict__ ws, float* __restrict__ out)
{
    __shared__ __align__(16) float tile[CIN][TROWS][TCOLS];
    __shared__ double sred[7][6];
    __shared__ int islast;

    const float* wc    = (const float*)(ws + WS_WC);
    const float* bias2 = (const float*)(ws + WS_BIAS2);
    const float* zp    = (const float*)(ws + WS_ZERO);
    const int* idxs    = (const int*)(ws + WS_IDX);
    float* part        = (float*)(ws + WS_PART);
    float* stats       = (float*)(ws + WS_STATS);
    int* cnt           = (int*)(ws + WS_CNT);

    int B = blockIdx.x;                        // 896 blocks, 896%8==0
    int work = (B & 7) * 112 + (B >> 3);
    int n = work / NSTR, strip = work - n*NSTR;
    int b = n / MM;
    int l = idxs[n];
    const float* src = x + (size_t)(b*LL + l) * (CIN*HW);
    float* ybase = out + (size_t)n * (COUT*HW);
    int x0col = strip*16 - 4;

    int tid = threadIdx.x;
    int r  = tid >> 2;
    int cg = tid & 3;

    float* tf = &tile[0][0][0];
    #pragma unroll
    for (int k = 0; k < 5; ++k) {
        CHUNK_ADDR;
        const float* pa = vld ? (src + off) : zp;
        float4 va = *(const float4*)pa;
        if (idx < NCHUNK) *(float4*)&tf[li] = va;
    }
    __syncthreads();

    float acc[4][3];
    #pragma unroll
    for (int p = 0; p < 4; ++p) { acc[p][0]=0.f; acc[p][1]=0.f; acc[p][2]=0.f; }

    #pragma unroll 1
    for (int cky = 0; cky < 21; ++cky) {
        int c = cky / 7, ky = cky % 7;
        const float* tr = &tile[c][r + ky][cg*4];
        float v[12];
        *(float4*)&v[0] = *(const float4*)&tr[0];
        *(float4*)&v[4] = *(const float4*)&tr[4];
        *(float4*)&v[8] = *(const float4*)&tr[8];
        const float* wrow = wc + cky*28;              // uniform -> s_load
        #pragma unroll
        for (int kx = 0; kx < 7; ++kx) {
            #pragma unroll
            for (int o = 0; o < 3; ++o) {
                float wv = wrow[kx*4 + o];            // SGPR operand
                #pragma unroll
                for (int p = 0; p < 4; ++p)
                    acc[p][o] += wv * v[p + kx + 1];
            }
        }
    }

    double sm0=0, sm1=0, sm2=0, sq0=0, sq1=0, sq2=0;
    float bb0 = bias2[0], bb1 = bias2[1], bb2 = bias2[2];
    int ocol = strip*16 + cg*4;
    float4 yv; float* pyv = (float*)&yv;
    #pragma unroll
    for (int p = 0; p < 4; ++p) {
        float val = acc[p][0] + bb0;
        pyv[p] = val; sm0 += val; sq0 += (double)val*val;
    }
    *(float4*)&ybase[0*HW + r*WW + ocol] = yv;
    #pragma unroll
    for (int p = 0; p < 4; ++p) {
        float val = acc[p][1] + bb1;
        pyv[p] = val; sm1 += val; sq1 += (double)val*val;
    }
    *(float4*)&ybase[1*HW + r*WW + ocol] = yv;
    #pragma unroll
    for (int p = 0; p < 4; ++p) {
        float val = acc[p][2] + bb2;
        pyv[p] = val; sm2 += val; sq2 += (double)val*val;
    }
    *(float4*)&ybase[2*HW + r*WW + ocol] = yv;

    double vals[6] = {sm0, sm1, sm2, sq0, sq1, sq2};
    #pragma unroll
    for (int j = 0; j < 6; ++j) {
        #pragma unroll
        for (int off2 = 32; off2 > 0; off2 >>= 1)
            vals[j] += __shfl_down(vals[j], off2, 64);
    }
    int wid = tid >> 6, lane = tid & 63;
    if (lane == 0) {
        #pragma unroll
        for (int j = 0; j < 6; ++j) sred[wid][j] = vals[j];
    }
    __syncthreads();
    if (tid < 6) {
        double s = 0.0;
        for (int w = 0; w < 7; ++w) s += sred[w][tid];
        part[B*6 + tid] = (float)s;
    }
    __syncthreads();

    // last-block ticket: the final block reduces part[896][6] -> stats
    if (tid == 0) {
        __threadfence();
        islast = (atomicAdd(cnt, 1) == BB*MM*NSTR - 1);
    }
    __syncthreads();
    if (islast && tid < 384) {
        __threadfence();                     // acquire: see all part writes
        int j = tid >> 6, ln = tid & 63;
        double s = 0.0;
        for (int nn = ln; nn < BB*MM*NSTR; nn += 64)
            s += (double)part[nn*6 + j];
        #pragma unroll
        for (int off2 = 32; off2 > 0; off2 >>= 1)
            s += __shfl_down(s, off2, 64);
        if (ln == 0) stats[j] = (float)s;
    }
}

// ---------------------------------------------------------------- finalize
__global__ __launch_bounds__(256) void finalize_kernel(
    const float* __restrict__ x, const float* __restrict__ gamma,
    const float* __restrict__ beta, const char* __restrict__ ws,
    float* __restrict__ out)
{
    const float* stats = (const float*)(ws + WS_STATS);
    const int* idxs    = (const int*)(ws + WS_IDX);
    int i4 = blockIdx.x * 256 + threadIdx.x;
    int i  = i4 * 4;
    int n  = i / (COUT*HW);
    int c  = (i / HW) % COUT;
    int hw = i % HW;
    int b  = n / MM;
    int l  = idxs[n];
    const float Ninv = 1.f / (float)(BB*MM*HW);
    float mean  = stats[c] * Ninv;
    float var   = stats[3+c] * Ninv - mean*mean;
    float scale = gamma[c] / sqrtf(var + BN_EPS);
    float shift = beta[c] - mean*scale;
    float4 y  = *(const float4*)&out[i];
    float4 xv = *(const float4*)&x[((size_t)(b*LL + l)*CIN + c)*HW + hw];
    float4 r;
    r.x = xv.x + fmaxf(y.x*scale + shift, 0.f);
    r.y = xv.y + fmaxf(y.y*scale + shift, 0.f);
    r.z = xv.z + fmaxf(y.z*scale + shift, 0.f);
    r.w = xv.w + fmaxf(y.w*scale + shift, 0.f);
    *(float4*)&out[i] = r;
}

// ---------------------------------------------------------------- launch
extern "C" void kernel_launch(void* const* d_in, const int* in_sizes, int n_in,
                              void* d_out, int out_size, void* d_ws, size_t ws_size,
                              hipStream_t stream)
{
    const float* x       = (const float*)d_in[0];
    const float* conv_w  = (const float*)d_in[1];
    const float* conv_b  = (const float*)d_in[2];
    const float* bneck_w = (const float*)d_in[3];
    const float* gamma   = (const float*)d_in[4];
    const float* beta    = (const float*)d_in[5];
    float* out = (float*)d_out;
    char* ws   = (char*)d_ws;

    prep_kernel<<<1, 256, 0, stream>>>(conv_w, conv_b, bneck_w, ws);
    score_kernel<<<BB*NP*NSTR, NTH, 0, stream>>>(x, ws);
    sample_kernel<<<1, 128, 0, stream>>>(ws);
    resconv_kernel<<<BB*MM*NSTR, NTH, 0, stream>>>(x, ws, out);
    int total4 = (BB*MM*COUT*HW) / 4;
    finalize_kernel<<<total4 / 256, 256, 0, stream>>>(x, gamma, beta, ws, out);
}

// Round 12
// 229.271 us; speedup vs baseline: 1.0857x; 1.0857x over previous
//
#include <hip/hip_runtime.h>
#include <math.h>

#define BB 8
#define LL 64
#define NP 63          // frame pairs per batch
#define MM 16          // sampled frames
#define HH 112
#define WW 112
#define HW (HH*WW)
#define CIN 3
#define CMID 8
#define COUT 3
#define NTH 448        // 112 rows x 4 col-groups of 4 px
#define TROWS 118      // 112 + 6 row halo
#define TCOLS 24       // 4 pad | 16 interior | 4 (incl right pad/halo)
#define NCHUNK 2124    // 3 * 118 * 6 float4-chunks
#define CPC 708        // chunks per channel (118*6)
#define NSTR 7         // column strips per frame

// workspace byte offsets
#define WS_SCORES 0        // double[504*7] = 28224
#define WS_IDX    28672    // int[128]
#define WS_WT     29184    // float[1176]  score weights [cky][kx][o=8]
#define WS_WC     34048    // float[588]   combined weights [cky][kx][o pad4]
#define WS_BIAS2  36480    // float[4]
#define WS_PART   36608    // float[896*6] = 21504 (ends 58112)
#define WS_STATS  58112    // float[6]
#define WS_ZERO   58368    // float[256] zero page

#define PD_EPS 1e-6f
#define BN_EPS 1e-5f

// ---------------------------------------------------------------- prep
__global__ void prep_kernel(const float* __restrict__ cw, const float* __restrict__ cb,
                            const float* __restrict__ bw, char* __restrict__ ws)
{
    float* wT = (float*)(ws + WS_WT);
    float* wc = (float*)(ws + WS_WC);
    float* b2 = (float*)(ws + WS_BIAS2);
    float* zp = (float*)(ws + WS_ZERO);
    int tid = threadIdx.x;
    zp[tid] = 0.f;
    for (int i = tid; i < CIN*49*CMID; i += 256) {
        int cky = i / 56, r = i % 56, kx = r / 8, o = r % 8;
        int c = cky / 7, ky = cky % 7;
        wT[i] = cw[((o*CIN + c)*7 + ky)*7 + kx];
    }
    for (int i = tid; i < CIN*49; i += 256) {
        int c = i / 49, ky = (i / 7) % 7, kx = i % 7;
        for (int o = 0; o < COUT; ++o) {
            float s = 0.f;
            for (int m = 0; m < CMID; ++m)
                s += bw[o*CMID + m] * cw[((m*CIN + c)*7 + ky)*7 + kx];
            wc[(c*7 + ky)*28 + kx*4 + o] = s;
        }
        wc[(c*7 + ky)*28 + kx*4 + 3] = 0.f;
    }
    if (tid < COUT) {
        float s = 0.f;
        for (int m = 0; m < CMID; ++m) s += bw[tid*CMID + m] * cb[m];
        b2[tid] = s;
    }
}

// chunk idx -> tile/global coords. tile row t <-> global row t-3.
#define CHUNK_ADDR                                                           \
    int idx = tid + k*NTH;                                                   \
    int c   = idx / CPC;                                                     \
    int rem = idx - c*CPC;                                                   \
    int row = rem / 6;                                                       \
    int q   = rem - row*6;                                                   \
    int gr  = row - 3;                                                       \
    int gc  = x0col + q*4;                                                   \
    bool vld = (idx < NCHUNK) & ((unsigned)gr < HH) & ((unsigned)gc <= 108); \
    int off = c*HW + gr*WW + gc;                                             \
    int li  = c*(TROWS*TCOLS) + row*TCOLS + q*4;

// ---------------------------------------------------------------- scores
// block = one pair x one 16-col full-height strip. Single LDS stage of the
// diff image, ONE barrier, barrier-free FMA phase; 4 blocks/CU = 28 waves.
// Weights via contiguous uniform s_load -> SGPR FMA operands.
__global__ __launch_bounds__(NTH) void score_kernel(
    const float* __restrict__ x, char* __restrict__ ws)
{
    __shared__ __align__(16) float tile[CIN][TROWS][TCOLS];   // 33984 B
    __shared__ double sred[7];
    const float* wT = (const float*)(ws + WS_WT);
    const float* zp = (const float*)(ws + WS_ZERO);
    double* scores  = (double*)(ws + WS_SCORES);

    int B = blockIdx.x;                        // 3528 blocks, 3528%8==0
    int work = (B & 7) * 441 + (B >> 3);       // XCD-chunked swizzle
    int pair = work / NSTR, strip = work - pair*NSTR;
    int b = pair / NP, t = pair - b*NP;
    const float* x0 = x + (size_t)(b*LL + t) * (CIN*HW);
    const float* x1 = x0 + CIN*HW;
    int x0col = strip*16 - 4;

    int tid = threadIdx.x;
    int r  = tid >> 2;          // output row 0..111
    int cg = tid & 3;           // col group

    float* tf = &tile[0][0][0];
    #pragma unroll
    for (int k = 0; k < 5; ++k) {
        CHUNK_ADDR;
        const float* pa = vld ? (x0 + off) : zp;
        const float* pb = vld ? (x1 + off) : zp;
        float4 va = *(const float4*)pa;
        float4 vb = *(const float4*)pb;
        float4 d;
        d.x = va.x - vb.x; d.y = va.y - vb.y;
        d.z = va.z - vb.z; d.w = va.w - vb.w;
        if (idx < NCHUNK) *(float4*)&tf[li] = d;
    }
    __syncthreads();

    float acc[4][8];
    #pragma unroll
    for (int p = 0; p < 4; ++p)
        #pragma unroll
        for (int o = 0; o < 8; ++o) acc[p][o] = 0.f;

    #pragma unroll 1
    for (int cky = 0; cky < 21; ++cky) {
        int c = cky / 7, ky = cky % 7;
        const float* tr = &tile[c][r + ky][cg*4];
        float v[12];
        *(float4*)&v[0] = *(const float4*)&tr[0];
        *(float4*)&v[4] = *(const float4*)&tr[4];
        *(float4*)&v[8] = *(const float4*)&tr[8];
        const float* wrow = wT + cky*56;              // uniform -> s_load
        #pragma unroll
        for (int kx = 0; kx < 7; ++kx) {
            #pragma unroll
            for (int o = 0; o < 8; ++o) {
                float wv = wrow[kx*8 + o];            // SGPR operand
                #pragma unroll
                for (int p = 0; p < 4; ++p)
                    acc[p][o] += wv * v[p + kx + 1];
            }
        }
    }

    double dacc = 0.0;
    #pragma unroll
    for (int p = 0; p < 4; ++p) {
        float ss = 0.f;
        #pragma unroll
        for (int o = 0; o < 8; ++o) {
            float d = acc[p][o] + PD_EPS;
            ss += d*d;
        }
        dacc += (double)sqrtf(ss);
    }

    #pragma unroll
    for (int off2 = 32; off2 > 0; off2 >>= 1)
        dacc += __shfl_down(dacc, off2, 64);
    int wid = tid >> 6, lane = tid & 63;
    if (lane == 0) sred[wid] = dacc;
    __syncthreads();
    if (tid == 0) {
        double ssum = 0.0;
        for (int w = 0; w < 7; ++w) ssum += sred[w];
        scores[pair*NSTR + strip] = ssum;
    }
}

// ---------------------------------------------------------------- sampling
__global__ void sample_kernel(char* __restrict__ ws)
{
    __shared__ double cum[BB][NP];
    const double* scores = (const double*)(ws + WS_SCORES);
    int* idxs = (int*)(ws + WS_IDX);
    int tid = threadIdx.x;                // 128
    if (tid < BB) {
        double tot = 0.0;
        for (int t = 0; t < NP; ++t) {
            const double* sp = scores + (tid*NP + t)*NSTR;
            double s = 0.0;
            for (int u = 0; u < NSTR; ++u) s += sp[u];
            tot += sqrt(s);
        }
        double run = 0.0;
        for (int t = 0; t < NP; ++t) {
            const double* sp = scores + (tid*NP + t)*NSTR;
            double s = 0.0;
            for (int u = 0; u < NSTR; ++u) s += sp[u];
            run += sqrt(s) / tot;
            cum[tid][t] = run;
        }
    }
    __syncthreads();
    {
        int b = tid / MM, m = tid % MM;
        double target = (double)((float)m / 15.f);
        int best = 0;
        double bv = fabs(cum[b][0] - target);
        for (int t = 1; t < NP; ++t) {
            double v = fabs(cum[b][t] - target);
            if (v < bv) { bv = v; best = t; }   // strict: first min wins
        }
        idxs[tid] = best;
    }
}

// ---------------------------------------------------------------- resblock conv
// block = one selected frame x one strip; single-stage structure.
// combined 7x7 3->3; y -> d_out + BN partials. No fences/atomics (the r11
// per-block threadfence+ticket cost ~27us in L2-writeback serialization).
__global__ __launch_bounds__(NTH) void resconv_kernel(
    const float* __restrict__ x, char* __restrict__ ws, float* __restrict__ out)
{
    __shared__ __align__(16) float tile[CIN][TROWS][TCOLS];
    __shared__ double sred[7][6];

    const float* wc    = (const float*)(ws + WS_WC);
    const float* bias2 = (const float*)(ws + WS_BIAS2);
    const float* zp    = (const float*)(ws + WS_ZERO);
    const int* idxs    = (const int*)(ws + WS_IDX);
    float* part        = (float*)(ws + WS_PART);

    int B = blockIdx.x;                        // 896 blocks, 896%8==0
    int work = (B & 7) * 112 + (B >> 3);
    int n = work / NSTR, strip = work - n*NSTR;
    int b = n / MM;
    int l = idxs[n];
    const float* src = x + (size_t)(b*LL + l) * (CIN*HW);
    float* ybase = out + (size_t)n * (COUT*HW);
    int x0col = strip*16 - 4;

    int tid = threadIdx.x;
    int r  = tid >> 2;
    int cg = tid & 3;

    float* tf = &tile[0][0][0];
    #pragma unroll
    for (int k = 0; k < 5; ++k) {
        CHUNK_ADDR;
        const float* pa = vld ? (src + off) : zp;
        float4 va = *(const float4*)pa;
        if (idx < NCHUNK) *(float4*)&tf[li] = va;
    }
    __syncthreads();

    float acc[4][3];
    #pragma unroll
    for (int p = 0; p < 4; ++p) { acc[p][0]=0.f; acc[p][1]=0.f; acc[p][2]=0.f; }

    #pragma unroll 1
    for (int cky = 0; cky < 21; ++cky) {
        int c = cky / 7, ky = cky % 7;
        const float* tr = &tile[c][r + ky][cg*4];
        float v[12];
        *(float4*)&v[0] = *(const float4*)&tr[0];
        *(float4*)&v[4] = *(const float4*)&tr[4];
        *(float4*)&v[8] = *(const float4*)&tr[8];
        const float* wrow = wc + cky*28;              // uniform -> s_load
        #pragma unroll
        for (int kx = 0; kx < 7; ++kx) {
            #pragma unroll
            for (int o = 0; o < 3; ++o) {
                float wv = wrow[kx*4 + o];            // SGPR operand
                #pragma unroll
                for (int p = 0; p < 4; ++p)
                    acc[p][o] += wv * v[p + kx + 1];
            }
        }
    }

    double sm0=0, sm1=0, sm2=0, sq0=0, sq1=0, sq2=0;
    float bb0 = bias2[0], bb1 = bias2[1], bb2 = bias2[2];
    int ocol = strip*16 + cg*4;
    float4 yv; float* pyv = (float*)&yv;
    #pragma unroll
    for (int p = 0; p < 4; ++p) {
        float val = acc[p][0] + bb0;
        pyv[p] = val; sm0 += val; sq0 += (double)val*val;
    }
    *(float4*)&ybase[0*HW + r*WW + ocol] = yv;
    #pragma unroll
    for (int p = 0; p < 4; ++p) {
        float val = acc[p][1] + bb1;
        pyv[p] = val; sm1 += val; sq1 += (double)val*val;
    }
    *(float4*)&ybase[1*HW + r*WW + ocol] = yv;
    #pragma unroll
    for (int p = 0; p < 4; ++p) {
        float val = acc[p][2] + bb2;
        pyv[p] = val; sm2 += val; sq2 += (double)val*val;
    }
    *(float4*)&ybase[2*HW + r*WW + ocol] = yv;

    double vals[6] = {sm0, sm1, sm2, sq0, sq1, sq2};
    #pragma unroll
    for (int j = 0; j < 6; ++j) {
        #pragma unroll
        for (int off2 = 32; off2 > 0; off2 >>= 1)
            vals[j] += __shfl_down(vals[j], off2, 64);
    }
    int wid = tid >> 6, lane = tid & 63;
    if (lane == 0) {
        #pragma unroll
        for (int j = 0; j < 6; ++j) sred[wid][j] = vals[j];
    }
    __syncthreads();
    if (tid < 6) {
        double s = 0.0;
        for (int w = 0; w < 7; ++w) s += sred[w][tid];
        part[B*6 + tid] = (float)s;
    }
}

// ---------------------------------------------------------------- stats reduce
__global__ void statreduce_kernel(char* __restrict__ ws)
{
    const float* part = (const float*)(ws + WS_PART);
    float* stats = (float*)(ws + WS_STATS);
    int tid = threadIdx.x;            // 384: 6 cols x 64 lanes
    int j = tid >> 6, lane = tid & 63;
    double s = 0.0;
    for (int n = lane; n < BB*MM*NSTR; n += 64) s += (double)part[n*6 + j];
    #pragma unroll
    for (int off = 32; off > 0; off >>= 1)
        s += __shfl_down(s, off, 64);
    if (lane == 0) stats[j] = (float)s;
}

// ---------------------------------------------------------------- finalize
__global__ __launch_bounds__(256) void finalize_kernel(
    const float* __restrict__ x, const float* __restrict__ gamma,
    const float* __restrict__ beta, const char* __restrict__ ws,
    float* __restrict__ out)
{
    const float* stats = (const float*)(ws + WS_STATS);
    const int* idxs    = (const int*)(ws + WS_IDX);
    int i4 = blockIdx.x * 256 + threadIdx.x;
    int i  = i4 * 4;
    int n  = i / (COUT*HW);
    int c  = (i / HW) % COUT;
    int hw = i % HW;
    int b  = n / MM;
    int l  = idxs[n];
    const float Ninv = 1.f / (float)(BB*MM*HW);
    float mean  = stats[c] * Ninv;
    float var   = stats[3+c] * Ninv - mean*mean;
    float scale = gamma[c] / sqrtf(var + BN_EPS);
    float shift = beta[c] - mean*scale;
    float4 y  = *(const float4*)&out[i];
    float4 xv = *(const float4*)&x[((size_t)(b*LL + l)*CIN + c)*HW + hw];
    float4 r;
    r.x = xv.x + fmaxf(y.x*scale + shift, 0.f);
    r.y = xv.y + fmaxf(y.y*scale + shift, 0.f);
    r.z = xv.z + fmaxf(y.z*scale + shift, 0.f);
    r.w = xv.w + fmaxf(y.w*scale + shift, 0.f);
    *(float4*)&out[i] = r;
}

// ---------------------------------------------------------------- launch
extern "C" void kernel_launch(void* const* d_in, const int* in_sizes, int n_in,
                              void* d_out, int out_size, void* d_ws, size_t ws_size,
                              hipStream_t stream)
{
    const float* x       = (const float*)d_in[0];
    const float* conv_w  = (const float*)d_in[1];
    const float* conv_b  = (const float*)d_in[2];
    const float* bneck_w = (const float*)d_in[3];
    const float* gamma   = (const float*)d_in[4];
    const float* beta    = (const float*)d_in[5];
    float* out = (float*)d_out;
    char* ws   = (char*)d_ws;

    prep_kernel<<<1, 256, 0, stream>>>(conv_w, conv_b, bneck_w, ws);
    score_kernel<<<BB*NP*NSTR, NTH, 0, stream>>>(x, ws);
    sample_kernel<<<1, 128, 0, stream>>>(ws);
    resconv_kernel<<<BB*MM*NSTR, NTH, 0, stream>>>(x, ws, out);
    statreduce_kernel<<<1, 384, 0, stream>>>(ws);
    int total4 = (BB*MM*COUT*HW) / 4;
    finalize_kernel<<<total4 / 256, 256, 0, stream>>>(x, gamma, beta, ws, out);
}